// Round 5
// baseline (63.876 us; speedup 1.0000x reference)
//
#include <hip/hip_runtime.h>

#define NB 8
#define NS 2048
#define ND 128
#define NK 16

typedef float f32x4 __attribute__((ext_vector_type(4)));

// Cross-lane fetch of a double from lane (lane ^ KIND).
// KIND 1,2: DPP quad_perm (VALU). KIND 4,8,16: ds_swizzle BitMode (within
// 32-lane group, xor<=16 stays inside). KIND 32: shfl across halves.
template <int KIND>
__device__ inline double partner_f64(double v) {
    const long long x = __double_as_longlong(v);
    int lo = (int)(unsigned int)x;
    int hi = (int)(x >> 32);
    if constexpr (KIND == 1) {
        lo = __builtin_amdgcn_update_dpp(0, lo, 0xB1, 0xF, 0xF, true);
        hi = __builtin_amdgcn_update_dpp(0, hi, 0xB1, 0xF, 0xF, true);
    } else if constexpr (KIND == 2) {
        lo = __builtin_amdgcn_update_dpp(0, lo, 0x4E, 0xF, 0xF, true);
        hi = __builtin_amdgcn_update_dpp(0, hi, 0x4E, 0xF, 0xF, true);
    } else if constexpr (KIND == 32) {
        lo = __shfl_xor(lo, 32, 64);
        hi = __shfl_xor(hi, 32, 64);
    } else {
        constexpr int imm = (KIND << 10) | 0x1F;   // BitMode xor mask
        lo = __builtin_amdgcn_ds_swizzle(lo, imm);
        hi = __builtin_amdgcn_ds_swizzle(hi, imm);
    }
    return __longlong_as_double(((long long)hi << 32) | (unsigned int)lo);
}

// Merge own sorted-16 with partner's sorted-16, keep lowest 16 (sorted).
// min(A[i], B[15-i]) is symmetric in A,B as a multiset -> both partners end
// with the SAME sorted low-16. After all 6 hypercube steps every lane holds
// the global sorted top-16.
template <int KIND>
__device__ inline void merge_step(double c[16]) {
    double b[16];
#pragma unroll
    for (int t = 0; t < 16; ++t) b[t] = partner_f64<KIND>(c[15 - t]);
#pragma unroll
    for (int t = 0; t < 16; ++t) c[t] = fmin(c[t], b[t]);   // bitonic low half
#pragma unroll
    for (int d = 8; d >= 1; d >>= 1) {                      // bitonic clean
#pragma unroll
        for (int t = 0; t < 16; ++t) {
            if ((t & d) == 0) {
                const double lo2 = fmin(c[t], c[t | d]);
                const double hi2 = fmax(c[t], c[t | d]);
                c[t] = lo2;
                c[t | d] = hi2;
            }
        }
    }
}

// Batcher odd-even mergesort of N keys (static indices, fully unrolled).
template <int N>
__device__ inline void batcher_sort(double* k) {
#pragma unroll
    for (int p = 1; p < N; p <<= 1) {
#pragma unroll
        for (int kk = p; kk >= 1; kk >>= 1) {
#pragma unroll
            for (int j = kk & (p - 1); j + kk < N; j += 2 * kk) {
#pragma unroll
                for (int ii = 0; ii < kk; ++ii) {
                    const int a = ii + j;
                    const int c = ii + j + kk;
                    if (c < N && (a / (2 * p)) == (c / (2 * p))) {
                        const double ka = k[a];
                        const double kc = k[c];
                        k[a] = fmin(ka, kc);
                        k[c] = fmax(ka, kc);
                    }
                }
            }
        }
    }
}

__global__ __launch_bounds__(256) void knn_kernel(
    const float* __restrict__ pts,   // [B,S,3]
    const int*   __restrict__ fidx,  // [B,S,1]
    const float* __restrict__ attr,  // [B,S,D]
    float*       __restrict__ out)   // out0 [B,S,K] | out1 [B,S,K] | out2 [B,S,K,D]
{
    const int lane = threadIdx.x & 63;
    const int row  = blockIdx.x * 4 + (threadIdx.x >> 6);   // [0, B*S)
    const int b = row >> 11;
    const int i = row & 2047;

    const float* pb = pts + (size_t)b * NS * 3;
    const float qx = pb[i * 3 + 0];
    const float qy = pb[i * 3 + 1];
    const float qz = pb[i * 3 + 2];

    // Monotone f64 key: bits = 0x3FF<<52 | dist_bits<<20 | j<<9.
    // Positive normal doubles in [1,2): f64 order == (dist_bits, j) lex order.
    double keys[32];
#pragma unroll
    for (int t = 0; t < 32; ++t) {
        const int j = t * 64 + lane;
        const float x = pb[j * 3 + 0];
        const float y = pb[j * 3 + 1];
        const float z = pb[j * 3 + 2];
        const float dx = __fsub_rn(qx, x);
        const float dy = __fsub_rn(qy, y);
        const float dz = __fsub_rn(qz, z);
        // exact left-to-right, no FMA contraction (matches reference arithmetic)
        float d = __fmul_rn(dx, dx);
        d = __fadd_rn(d, __fmul_rn(dy, dy));
        d = __fadd_rn(d, __fmul_rn(dz, dz));
        const unsigned int db = __float_as_uint(d);
        const unsigned int hi = 0x3FF00000u | (db >> 12);
        const unsigned int lo = (db << 20) | ((unsigned int)j << 9);
        keys[t] = __longlong_as_double(((long long)hi << 32) | lo);
    }

    // Per-lane top-16 of 32, sorted ascending.
    batcher_sort<16>(keys);        // keys[0..15] asc
    batcher_sort<16>(keys + 16);   // keys[16..31] asc
    double c[16];
#pragma unroll
    for (int t = 0; t < 16; ++t) c[t] = fmin(keys[t], keys[31 - t]);  // bitonic low half
#pragma unroll
    for (int d = 8; d >= 1; d >>= 1) {                                // bitonic clean
#pragma unroll
        for (int t = 0; t < 16; ++t) {
            if ((t & d) == 0) {
                const double ka = c[t];
                const double kc = c[t | d];
                c[t] = fmin(ka, kc);
                c[t | d] = fmax(ka, kc);
            }
        }
    }

    // Hypercube merge-tree: 6 steps, after which ALL lanes hold the global
    // sorted top-16. No LDS, no serial tournament, no pops.
    merge_step<1>(c);
    merge_step<2>(c);
    merge_step<4>(c);
    merge_step<8>(c);
    merge_step<16>(c);
    merge_step<32>(c);

    // Decode winners (uniform across the wave, all indices static).
    int jk[16];
    float dk[16];
#pragma unroll
    for (int k = 0; k < 16; ++k) {
        const long long kb = __double_as_longlong(c[k]);
        jk[k] = (int)((kb >> 9) & 0x7FF);
        dk[k] = __uint_as_float((unsigned int)(kb >> 20));
    }

    float* out0 = out;                                   // [B,S,K]
    float* out1 = out + (size_t)NB * NS * NK;            // [B,S,K]
    float* out2 = out + (size_t)2 * NB * NS * NK;        // [B,S,K,D]
    const size_t rowBase = (size_t)row * NK;

    float d_sel = 0.0f;
    int j_sel = 0;
#pragma unroll
    for (int k = 0; k < 16; ++k) {
        if (lane == k) { d_sel = dk[k]; j_sel = jk[k]; }
    }
    if (lane < NK) {
        out0[rowBase + lane] = d_sel;
        const int ii = fidx[(size_t)b * NS + i];
        const int jj = fidx[(size_t)b * NS + j_sel];
        out1[rowBase + lane] = fabsf((float)(ii - jj));
    }

    // Gather attribute rows: 2 neighbor rows per pass (512B each); issue all
    // 8 loads, then all 8 stores.
    const int half = lane >> 5;      // 0 or 1
    const int comp = lane & 31;      // float4 slot within the 128-float row
    const float* ab = attr + (size_t)b * NS * ND;
    float* o2row = out2 + rowBase * ND;

    f32x4 v[8];
#pragma unroll
    for (int p = 0; p < 8; ++p) {
        const int jj = half ? jk[2 * p + 1] : jk[2 * p];
        v[p] = *(const f32x4*)(ab + (size_t)jj * ND + comp * 4);
    }
#pragma unroll
    for (int p = 0; p < 8; ++p) {
        *(f32x4*)(o2row + (size_t)(2 * p + half) * ND + comp * 4) = v[p];
    }
}

extern "C" void kernel_launch(void* const* d_in, const int* in_sizes, int n_in,
                              void* d_out, int out_size, void* d_ws, size_t ws_size,
                              hipStream_t stream) {
    const float* pts  = (const float*)d_in[0];
    const int*   fidx = (const int*)d_in[1];
    const float* attr = (const float*)d_in[2];
    float* out = (float*)d_out;

    const int rows = NB * NS;                 // 16384
    const int blocks = rows / 4;              // 4096 blocks, 4 waves each
    knn_kernel<<<blocks, 256, 0, stream>>>(pts, fidx, attr, out);
}

// Round 6
// 40.395 us; speedup vs baseline: 1.5813x; 1.5813x over previous
//
#include <hip/hip_runtime.h>

#define NB 8
#define NS 2048
#define ND 128
#define NK 16

typedef float f32x4 __attribute__((ext_vector_type(4)));

// ---- cross-lane partner fetch (lane ^ KIND), proven in R3/R5 ----
template <int KIND>
__device__ inline int partner_i32(int v) {
    if constexpr (KIND == 1) {
        return __builtin_amdgcn_update_dpp(0, v, 0xB1, 0xF, 0xF, true);   // quad_perm xor1
    } else if constexpr (KIND == 2) {
        return __builtin_amdgcn_update_dpp(0, v, 0x4E, 0xF, 0xF, true);   // quad_perm xor2
    } else if constexpr (KIND == 32) {
        return __shfl_xor(v, 32, 64);
    } else {
        constexpr int imm = (KIND << 10) | 0x1F;                          // ds_swizzle BitMode
        return __builtin_amdgcn_ds_swizzle(v, imm);
    }
}
template <int KIND>
__device__ inline float partner_f32(float v) {
    return __int_as_float(partner_i32<KIND>(__float_as_int(v)));
}
template <int KIND>
__device__ inline double partner_f64(double v) {
    const long long x = __double_as_longlong(v);
    const int lo = partner_i32<KIND>((int)(unsigned int)x);
    const int hi = partner_i32<KIND>((int)(x >> 32));
    return __longlong_as_double(((long long)hi << 32) | (unsigned int)lo);
}
__device__ inline float partner_f32_dyn(float v, int d) {
    switch (d) {
    case 1:  return partner_f32<1>(v);
    case 2:  return partner_f32<2>(v);
    case 4:  return partner_f32<4>(v);
    case 8:  return partner_f32<8>(v);
    case 16: return partner_f32<16>(v);
    default: return partner_f32<32>(v);
    }
}
__device__ inline double partner_f64_dyn(double v, int d) {
    switch (d) {
    case 1:  return partner_f64<1>(v);
    case 2:  return partner_f64<2>(v);
    case 4:  return partner_f64<4>(v);
    case 8:  return partner_f64<8>(v);
    case 16: return partner_f64<16>(v);
    default: return partner_f64<32>(v);
    }
}
__device__ inline double shfl_idx_f64(double v, int src) {
    const long long x = __double_as_longlong(v);
    const int lo = __shfl((int)(unsigned int)x, src, 64);
    const int hi = __shfl((int)(x >> 32), src, 64);
    return __longlong_as_double(((long long)hi << 32) | (unsigned int)lo);
}

// Full bitonic sort across 64 lanes, ascending by lane. 21 stages.
__device__ inline float bitonic_sort64_f32(float v, int lane) {
#pragma unroll
    for (int k = 2; k <= 64; k <<= 1) {
#pragma unroll
        for (int d = k >> 1; d >= 1; d >>= 1) {
            const float o = partner_f32_dyn(v, d);
            const float mn = fminf(v, o);
            const float mx = fmaxf(v, o);
            const bool keepMin = ((lane & k) == 0) == ((lane & d) == 0);
            v = keepMin ? mn : mx;
        }
    }
    return v;
}
__device__ inline double bitonic_sort64_f64(double v, int lane) {
#pragma unroll
    for (int k = 2; k <= 64; k <<= 1) {
#pragma unroll
        for (int d = k >> 1; d >= 1; d >>= 1) {
            const double o = partner_f64_dyn(v, d);
            const double mn = fmin(v, o);
            const double mx = fmax(v, o);
            const bool keepMin = ((lane & k) == 0) == ((lane & d) == 0);
            v = keepMin ? mn : mx;
        }
    }
    return v;
}

__global__ __launch_bounds__(256) void knn_kernel(
    const float* __restrict__ pts,   // [B,S,3]
    const int*   __restrict__ fidx,  // [B,S,1]
    const float* __restrict__ attr,  // [B,S,D]
    float*       __restrict__ out)   // out0 [B,S,K] | out1 [B,S,K] | out2 [B,S,K,D]
{
    __shared__ float spts[NS * 3];        // 24576 B: the block's batch points
    __shared__ double sbuf[4][66];        // per-wave survivor window [0..63] + dump [64]

    const int tid  = threadIdx.x;
    const int wv   = tid >> 6;
    const int lane = tid & 63;
    const int row  = blockIdx.x * 4 + wv;   // 4 rows/block, same batch (2048 % 4 == 0)
    const int b = row >> 11;
    const int i = row & 2047;

    // Stage the batch's 2048 points (24 KB) into LDS, coalesced f32x4.
    {
        const f32x4* src = (const f32x4*)(pts + (size_t)b * NS * 3);
        f32x4* dst = (f32x4*)spts;
#pragma unroll
        for (int k = 0; k < 6; ++k) dst[k * 256 + tid] = src[k * 256 + tid];
    }
    __syncthreads();

    const float qx = spts[i * 3 + 0];
    const float qy = spts[i * 3 + 1];
    const float qz = spts[i * 3 + 2];

    // Per-lane distances for j = t*64 + lane; track lane min.
    float dist[32];
    float m = 3.4e38f;
#pragma unroll
    for (int t = 0; t < 32; ++t) {
        const int j = t * 64 + lane;
        const float x = spts[j * 3 + 0];
        const float y = spts[j * 3 + 1];
        const float z = spts[j * 3 + 2];
        const float dx = __fsub_rn(qx, x);
        const float dy = __fsub_rn(qy, y);
        const float dz = __fsub_rn(qz, z);
        // exact left-to-right, no FMA contraction (matches reference arithmetic)
        float d = __fmul_rn(dx, dx);
        d = __fadd_rn(d, __fmul_rn(dy, dy));
        d = __fadd_rn(d, __fmul_rn(dz, dz));
        dist[t] = d;
        m = fminf(m, d);
    }

    // T = 16th smallest lane-min. The 16 lanes with smallest minima each hold
    // >=1 distinct element <= T, so every true top-16 element has dist <= T.
    const float ms = bitonic_sort64_f32(m, lane);
    const float T = __shfl(ms, 15, 64);

    // Chunked exact selection over survivors (dist <= T). Expected M ~ 18,
    // so the loop runs once; the windowed re-compaction keeps it exact for
    // any M.
    double* sw = &sbuf[wv][0];
    const double INF = __longlong_as_double(0x7FF0000000000000LL);
    double r = INF;                 // lanes 0..15: global sorted top-16 so far
    for (int c0 = 0;; c0 += 64) {
        sw[lane] = INF;             // init window (in-order LDS per wave)
        int base = 0;
#pragma unroll
        for (int t = 0; t < 32; ++t) {
            const bool pred = (dist[t] <= T);
            const unsigned long long bal = __ballot(pred);
            const int rank = __builtin_amdgcn_mbcnt_hi(
                (unsigned int)(bal >> 32),
                __builtin_amdgcn_mbcnt_lo((unsigned int)bal, 0));
            const int slot = base + rank;
            const bool inw = pred && ((unsigned int)(slot - c0) < 64u);
            // Monotone f64 key: hi = dist_bits + 0x10000000 (normal, positive),
            // lo = j. f64 order == (dist, j) lex order; all keys distinct.
            const unsigned int hi = __float_as_uint(dist[t]) + 0x10000000u;
            const unsigned int lo = (unsigned int)(t * 64) | (unsigned int)lane;
            const double kd = __longlong_as_double(((long long)hi << 32) | lo);
            sw[inw ? (slot - c0) : 64] = kd;
            base += (int)__popcll(bal);
        }
        const int M = base;         // wave-uniform total survivor count (>= 16)
        asm volatile("s_waitcnt lgkmcnt(0)" ::: "memory");
        double v = sw[lane];
        v = bitonic_sort64_f64(v, lane);
        if (c0 == 0) {
            r = v;
        } else {
            // merge-low-16: r(16, lanes 0..15) with v's low-16 (lanes 0..15)
            double s = shfl_idx_f64(v, (15 - lane) & 63);
            double ml = fmin(r, s);
#pragma unroll
            for (int d = 8; d >= 1; d >>= 1) {
                const double o = partner_f64_dyn(ml, d);
                const double mn = fmin(ml, o);
                const double mx = fmax(ml, o);
                ml = ((lane & d) == 0) ? mn : mx;
            }
            r = ml;
        }
        if (M <= c0 + 64) break;
    }

    // Decode: lane k (k<16) holds winner k.
    const long long kb = __double_as_longlong(r);
    const int jsel = (int)(unsigned int)kb;                       // low word = j
    const unsigned int db = (unsigned int)((unsigned long long)kb >> 32) - 0x10000000u;

    float* out0 = out;                                   // [B,S,K]
    float* out1 = out + (size_t)NB * NS * NK;            // [B,S,K]
    float* out2 = out + (size_t)2 * NB * NS * NK;        // [B,S,K,D]
    const size_t rowBase = (size_t)row * NK;

    if (lane < NK) {
        out0[rowBase + lane] = __uint_as_float(db);
        const int ii = fidx[(size_t)b * NS + i];
        const int jj = fidx[(size_t)b * NS + jsel];
        out1[rowBase + lane] = fabsf((float)(ii - jj));
    }

    // Gather attribute rows: 2 neighbor rows per pass (512B each).
    const int half = lane >> 5;      // 0 or 1
    const int comp = lane & 31;      // float4 slot within the 128-float row
    const float* ab = attr + (size_t)b * NS * ND;
    float* o2row = out2 + rowBase * ND;

    int jj8[8];
#pragma unroll
    for (int p = 0; p < 8; ++p) jj8[p] = __shfl(jsel, 2 * p + half, 64);
    f32x4 v8[8];
#pragma unroll
    for (int p = 0; p < 8; ++p)
        v8[p] = *(const f32x4*)(ab + (size_t)jj8[p] * ND + comp * 4);
#pragma unroll
    for (int p = 0; p < 8; ++p)
        *(f32x4*)(o2row + (size_t)(2 * p + half) * ND + comp * 4) = v8[p];
}

extern "C" void kernel_launch(void* const* d_in, const int* in_sizes, int n_in,
                              void* d_out, int out_size, void* d_ws, size_t ws_size,
                              hipStream_t stream) {
    const float* pts  = (const float*)d_in[0];
    const int*   fidx = (const int*)d_in[1];
    const float* attr = (const float*)d_in[2];
    float* out = (float*)d_out;

    const int rows = NB * NS;                 // 16384
    const int blocks = rows / 4;              // 4096 blocks, 4 waves each
    knn_kernel<<<blocks, 256, 0, stream>>>(pts, fidx, attr, out);
}